// Round 5
// baseline (70.817 us; speedup 1.0000x reference)
//
#include <hip/hip_runtime.h>
#include <math.h>

#define M 64
#define NSEG 16
#define NS 2                 // i-split: 2 blocks per sample, 32-deep each (1 block/CU)
#define NCHUNK 544           // upper-triangle chunks (j, k0=4*kt), kt >= jt = j/4
#define SSTRIDE 65           // sim LDS row stride (bank spread for mirror writes)

// chunk c -> (j, k0): tile = c>>2 indexes upper-tri of 16x16 (jt<=kt), r = c&3.
__device__ __forceinline__ void decode_chunk(int c, int& j, int& k0) {
    const int tile = c >> 2;
    const int r = c & 3;
    int jt = 0, cum = 0;
    #pragma unroll
    for (int g = 1; g <= 15; ++g) {
        const int Tg = 16 * g - ((g * (g - 1)) >> 1);
        if (tile >= Tg) { jt = g; cum = Tg; }
    }
    const int kt = jt + (tile - cum);
    j  = (jt << 2) + r;
    k0 = kt << 2;
}

#define STAGE_TABLES()                                                            \
    if (t < 8) {                                                                  \
        float wv[NSEG + 1];                                                       \
        float ssum = 0.f;                                                         \
        _Pragma("unroll")                                                         \
        for (int i = 0; i <= NSEG; ++i) { wv[i] = fabsf(fw[t*(NSEG+1)+i]); ssum += wv[i]; } \
        const float inv = 1.0f / ssum;                                            \
        _Pragma("unroll")                                                         \
        for (int i = 0; i <= NSEG; ++i) wv[i] *= inv;                             \
        float csum = 0.f;                                                         \
        _Pragma("unroll")                                                         \
        for (int i = 0; i <= NSEG; ++i) {                                         \
            csum += wv[i];                                                        \
            cw_s[t][i] = make_float2(csum, wv[i < NSEG ? i + 1 : NSEG]);          \
        }                                                                         \
    }

#define DEF_PLINS()                                                               \
    auto plin = [&](int kk, float x) -> float {                                   \
        const float y = 16.0f * x;                                                \
        const float fi = floorf(y);                                               \
        const int idx = (int)fi;                                                  \
        const float2 cw = cw_s[kk][idx];                                          \
        return cw.x + (y - fi) * cw.y;                                            \
    };                                                                            \
    auto plin2d = [&](float d) -> float {                                         \
        const float y = fmaf(-16.0f, d, 16.0f);                                   \
        int idx = (int)y;                 /* trunc: (-eps) -> 0, in-bounds */     \
        const float fr = y - floorf(y);   /* floor: matches reference frac */     \
        const float2 cw = cw_s[2][idx];                                           \
        return cw.x + fr * cw.y;                                                  \
    };

// ---- Kernel 1: pairs phase reads geometry straight from global (bk coalesced,
// bi wave-uniform, L1-resident) and writes the ds matrix to a per-block global
// scratch (8 KB, L1-resident). Triangle then reads aij/kv from GLOBAL (vmem
// pipe) while the LDS pipe serves only the per-element table gathers — the two
// pipes overlap instead of serializing on LDS. Block-private scratch + reads
// only after __syncthreads() => workgroup-scope visibility, no cross-block
// coherence involved. All arithmetic op-identical to round 4 (absmax 0.0).
__global__ __launch_bounds__(1024, 4)
void k1_partial(const float* __restrict__ boxes,
                const float* __restrict__ attn,
                const float* __restrict__ fw,
                float4* __restrict__ ws4,
                float* __restrict__ ws_a,
                float* __restrict__ ws_dc,
                float* __restrict__ ws_ds)
{
    __shared__ float2 cw_s[8][NSEG + 1];

    const int n = blockIdx.x;
    const int s = blockIdx.y;
    const int t = threadIdx.x;

    STAGE_TABLES();
    __syncthreads();
    DEF_PLINS();

    float* __restrict__ dsg = ws_ds + (n * NS + s) * 2048;   // this block's 32 i-rows
    const float* __restrict__ bx = boxes + n * 4 * M;
    const float* __restrict__ at = attn + n * M;

    // pairs (i,k) with i in [32s, 32s+32): ds rows (global scratch) + A + dist-conf
    float dc_local = 0.f;
    #pragma unroll
    for (int it = 0; it < 2; ++it) {
        const int p2 = it * 1024 + t;          // 0..2047 local pair
        const int p  = s * 2048 + p2;          // global pair
        const int i  = p >> 6, k = p & (M - 1);
        // i-side: wave-uniform address (i constant within a wave) -> broadcast line
        const float ix1 = bx[0*M + i], iy1 = bx[1*M + i];
        const float ix2 = bx[2*M + i], iy2 = bx[3*M + i];
        // k-side: k = lane -> perfectly coalesced
        const float kx1 = bx[0*M + k], ky1 = bx[1*M + k];
        const float kx2 = bx[2*M + k], ky2 = bx[3*M + k];
        const float ai = at[i], ak = at[k];
        const float area_i = fmaxf(ix2 - ix1, 0.f) * fmaxf(iy2 - iy1, 0.f);
        const float area_k = fmaxf(kx2 - kx1, 0.f) * fmaxf(ky2 - ky1, 0.f);
        const float rel = ai * ak;
        const float mx = fmaxf(ix1, kx1);
        const float my = fmaxf(iy1, ky1);
        const float Mx = fminf(ix2, kx2);
        const float My = fminf(iy2, ky2);
        const float inter = fmaxf(Mx - mx, 0.f) * fmaxf(My - my, 0.f);
        const float iou = inter / (area_i + area_k - inter + 1e-12f);
        const float dist = 1.0f - iou;
        dsg[p2] = plin(3, rel) * plin(4, dist);
        ws_a[n * (M * M) + p] = plin(0, rel) * plin(1, dist);
        dc_local += fabsf(plin(6, dist) - 0.5f);
    }
    {
        float vA = dc_local;
        #pragma unroll
        for (int off = 32; off > 0; off >>= 1) vA += __shfl_down(vA, off, 64);
        if ((t & 63) == 0) ws_dc[n * 32 + s * 16 + (t >> 6)] = vA;
    }
    __syncthreads();   // dsg writes visible block-wide (drains vmcnt + barrier)

    // triangle product: chunk t (t<544), 32-deep i; data from global (vmem pipe,
    // L1-resident), table gathers from LDS (ds pipe) -> pipes overlap.
    if (t < NCHUNK) {
        int j, k0;
        decode_chunk(t, j, k0);
        float p0 = 1.f, p1 = 1.f, p2 = 1.f, p3 = 1.f;
        #pragma unroll 8
        for (int ii = 0; ii < 32; ++ii) {
            const float aij = dsg[ii * M + j];
            const float4 kv = *(const float4*)&dsg[ii * M + k0];
            p0 *= plin2d(fabsf(aij - kv.x));
            p1 *= plin2d(fabsf(aij - kv.y));
            p2 *= plin2d(fabsf(aij - kv.z));
            p3 *= plin2d(fabsf(aij - kv.w));
        }
        ws4[(n * NS + s) * NCHUNK + t] = make_float4(p0, p1, p2, p3);
    }
}

// ---- Kernel 2: combine partials, row sums, score from precomputed A, epilogue.
// (unchanged from round 4 -- all global reads hoisted to the top)
__global__ __launch_bounds__(1024, 4)
void k2_finish(const float* __restrict__ attn,
               const float* __restrict__ fw,
               const float4* __restrict__ ws4,
               const float* __restrict__ ws_a,
               const float* __restrict__ ws_dc,
               float* __restrict__ out)
{
    __shared__ float2 cw_s[8][NSEG + 1];
    __shared__ float att_s[M];
    __shared__ float sim_s[M * SSTRIDE];
    __shared__ float invrs_s[M];
    __shared__ float redB_s[16], redC_s[16];
    __shared__ float redD_s;
    __shared__ float bcast_s[3];

    const int n = blockIdx.x;
    const int t = threadIdx.x;

    // hoisted global loads: independent of all LDS staging
    int j = 0, k0 = 0;
    float4 v0, v1;
    if (t < NCHUNK) {
        decode_chunk(t, j, k0);
        v0 = ws4[(n * NS + 0) * NCHUNK + t];
        v1 = ws4[(n * NS + 1) * NCHUNK + t];
    }
    float av[4];
    #pragma unroll
    for (int it = 0; it < 4; ++it) av[it] = ws_a[n * (M * M) + it * 1024 + t];
    float dcv = (t < 32) ? ws_dc[n * 32 + t] : 0.f;

    STAGE_TABLES();
    if (t < M) att_s[t] = attn[n * M + t];
    __syncthreads();
    DEF_PLINS();

    // att-conf partial + dist-conf combine (wave 0 holds dcv)
    {
        float vB = (t < M) ? fabsf(plin(5, att_s[t]) - 0.5f) : 0.f;
        #pragma unroll
        for (int off = 32; off > 0; off >>= 1) vB += __shfl_down(vB, off, 64);
        if ((t & 63) == 0) redB_s[t >> 6] = vB;
    }
    if (t < 64) {
        float vD = dcv;
        #pragma unroll
        for (int off = 32; off > 0; off >>= 1) vD += __shfl_down(vD, off, 64);
        if (t == 0) redD_s = vD;
    }

    // combine the NS partial products, apply att factor, scatter direct + mirror
    if (t < NCHUNK) {
        const float aj = att_s[j];
        float sv[4];
        sv[0] = v0.x * v1.x * plin2d(fabsf(aj - att_s[k0 + 0]));
        sv[1] = v0.y * v1.y * plin2d(fabsf(aj - att_s[k0 + 1]));
        sv[2] = v0.z * v1.z * plin2d(fabsf(aj - att_s[k0 + 2]));
        sv[3] = v0.w * v1.w * plin2d(fabsf(aj - att_s[k0 + 3]));
        #pragma unroll
        for (int q = 0; q < 4; ++q) {
            const int k = k0 + q;
            sim_s[j * SSTRIDE + k] = sv[q];   // direct
            sim_s[k * SSTRIDE + j] = sv[q];   // mirror (bit-identical by |a-b| symmetry)
        }
    }
    __syncthreads();

    // row sums -> invrs
    {
        const int jr = t >> 4, c = t & 15;
        float psum = sim_s[jr * SSTRIDE + c] + sim_s[jr * SSTRIDE + c + 16] +
                     sim_s[jr * SSTRIDE + c + 32] + sim_s[jr * SSTRIDE + c + 48];
        #pragma unroll
        for (int off = 8; off > 0; off >>= 1) psum += __shfl_down(psum, off, 64);
        if (c == 0) invrs_s[jr] = 1.0f / psum;
    }
    __syncthreads();

    // score pass: A values already in registers
    float sc_local = 0.f;
    #pragma unroll
    for (int it = 0; it < 4; ++it) {
        const int p = it * 1024 + t;
        sc_local += av[it] * (invrs_s[p >> 6] * invrs_s[p & (M - 1)]);
    }
    if (t < M) sc_local += plin(0, att_s[t] * att_s[t]) * invrs_s[t];
    {
        float vC = sc_local;
        #pragma unroll
        for (int off = 32; off > 0; off >>= 1) vC += __shfl_down(vC, off, 64);
        if ((t & 63) == 0) redC_s[t >> 6] = vC;
    }
    __syncthreads();

    if (t == 0) {
        float score_sum = 0.f, acs = 0.f;
        #pragma unroll
        for (int w = 0; w < 16; ++w) { score_sum += redC_s[w]; acs += redB_s[w]; }
        const float dcs = redD_s;
        const float score = sqrtf(score_sum + 1e-20f);
        const float conf = plin(7, acs * (1.0f / M) + dcs * (1.0f / (M * M)));
        const float scc = fminf(fmaxf(score, 0.f), 10.0f);
        const float fl = floorf(scc);
        bcast_s[0] = conf; bcast_s[1] = fl; bcast_s[2] = scc - fl;
    }
    __syncthreads();

    if (t < 11) {
        const float conf = bcast_s[0];
        const int i0 = (int)bcast_s[1];
        const float frac = bcast_s[2];
        const int i1 = i0 > 10 ? 10 : i0;
        const int i2 = (i0 + 1) > 10 ? 10 : (i0 + 1);
        float v = 0.f;
        if (t == i1) v += 1.0f - frac;
        if (t == i2) v += frac;
        out[n * 11 + t] = v * conf;
    }
}

extern "C" void kernel_launch(void* const* d_in, const int* in_sizes, int n_in,
                              void* d_out, int out_size, void* d_ws, size_t ws_size,
                              hipStream_t stream) {
    const float* boxes = (const float*)d_in[0];   // (n,4,64) f32
    const float* attn  = (const float*)d_in[1];   // (n,64)   f32
    const float* fw    = (const float*)d_in[2];   // (16,17)  f32
    float* out = (float*)d_out;                   // (n,11)   f32
    const int n = in_sizes[1] / M;

    float4* ws4  = (float4*)d_ws;                           // n*NS*NCHUNK float4 ~ 2.2 MB
    float* ws_a  = (float*)((char*)d_ws + (4u << 20));      // n*4096 floats = 2 MB at +4 MB
    float* ws_dc = (float*)((char*)d_ws + (8u << 20));      // n*32 floats at +8 MB
    float* ws_ds = (float*)((char*)d_ws + (9u << 20));      // n*NS*2048 floats = 2 MB at +9 MB

    k1_partial<<<dim3(n, NS), dim3(1024), 0, stream>>>(boxes, attn, fw, ws4, ws_a, ws_dc, ws_ds);
    k2_finish<<<dim3(n), dim3(1024), 0, stream>>>(attn, fw, ws4, ws_a, ws_dc, out);
}

// Round 7
// 70.038 us; speedup vs baseline: 1.0111x; 1.0111x over previous
//
#include <hip/hip_runtime.h>
#include <math.h>

#define M 64
#define NSEG 16
#define NS 2                 // i-split: 2 blocks per sample, 32-deep each (1 block/CU)
#define NCHUNK 544           // upper-triangle chunks (j, k0=4*kt), kt >= jt = j/4
#define SSTRIDE 65           // sim LDS row stride (bank spread for mirror writes)

// chunk c -> (j, k0): tile = c>>2 indexes upper-tri of 16x16 (jt<=kt), r = c&3.
__device__ __forceinline__ void decode_chunk(int c, int& j, int& k0) {
    const int tile = c >> 2;
    const int r = c & 3;
    int jt = 0, cum = 0;
    #pragma unroll
    for (int g = 1; g <= 15; ++g) {
        const int Tg = 16 * g - ((g * (g - 1)) >> 1);
        if (tile >= Tg) { jt = g; cum = Tg; }
    }
    const int kt = jt + (tile - cum);
    j  = (jt << 2) + r;
    k0 = kt << 2;
}

#define STAGE_TABLES()                                                            \
    if (t < 8) {                                                                  \
        float wv[NSEG + 1];                                                       \
        float ssum = 0.f;                                                         \
        _Pragma("unroll")                                                         \
        for (int i = 0; i <= NSEG; ++i) { wv[i] = fabsf(fw[t*(NSEG+1)+i]); ssum += wv[i]; } \
        const float inv = 1.0f / ssum;                                            \
        _Pragma("unroll")                                                         \
        for (int i = 0; i <= NSEG; ++i) wv[i] *= inv;                             \
        float csum = 0.f;                                                         \
        _Pragma("unroll")                                                         \
        for (int i = 0; i <= NSEG; ++i) {                                         \
            csum += wv[i];                                                        \
            cw_s[t][i] = make_float2(csum, wv[i < NSEG ? i + 1 : NSEG]);          \
        }                                                                         \
    }

#define DEF_PLINS()                                                               \
    auto plin = [&](int kk, float x) -> float {                                   \
        const float y = 16.0f * x;                                                \
        const float fi = floorf(y);                                               \
        const int idx = (int)fi;                                                  \
        const float2 cw = cw_s[kk][idx];                                          \
        return cw.x + (y - fi) * cw.y;                                            \
    };                                                                            \
    auto plin2d = [&](float d) -> float {                                         \
        const float y = fmaf(-16.0f, d, 16.0f);                                   \
        int idx = (int)y;                 /* trunc: (-eps) -> 0, in-bounds */     \
        const float fr = y - floorf(y);   /* floor: matches reference frac */     \
        const float2 cw = cw_s[2][idx];                                           \
        return cw.x + fr * cw.y;                                                  \
    };

// ---- Kernel 1: half-staging (own 32 i-rows) + A matrix + dist-conf + triangle.
// 256 blocks = exactly 1 block/CU: each CU's LDS pipe serves one depth-32 triangle
// (the phase is LDS-issue bound; this is the unique full-spread configuration).
// Table gathers are broadcast-dominated (<=17 distinct addrs/wave) => conflict-free;
// do NOT replicate tables (breaks broadcast) or move data to vmem (R5: neutral-neg).
__global__ __launch_bounds__(1024, 4)
void k1_partial(const float* __restrict__ boxes,
                const float* __restrict__ attn,
                const float* __restrict__ fw,
                float4* __restrict__ ws4,
                float* __restrict__ ws_a,
                float* __restrict__ ws_dc)
{
    __shared__ float2 cw_s[8][NSEG + 1];
    __shared__ float4 box_s[M];          // (x1,y1,x2,y2) -> 1 b128 per side
    __shared__ float2 af_s[M];           // (att, area)   -> 1 b64 per side
    __shared__ float ds_s[32 * M];       // only this block's 32 i-rows

    const int n = blockIdx.x;
    const int s = blockIdx.y;
    const int t = threadIdx.x;

    STAGE_TABLES();
    if (t < M) {
        const float a  = attn[n * M + t];
        const float xa = boxes[n*4*M + 0*M + t];
        const float ya = boxes[n*4*M + 1*M + t];
        const float xb = boxes[n*4*M + 2*M + t];
        const float yb = boxes[n*4*M + 3*M + t];
        box_s[t] = make_float4(xa, ya, xb, yb);
        af_s[t]  = make_float2(a, fmaxf(xb - xa, 0.f) * fmaxf(yb - ya, 0.f));
    }
    __syncthreads();
    DEF_PLINS();

    // pairs (i,k) with i in [32s, 32s+32): ds rows + A + dist-conf
    float dc_local = 0.f;
    #pragma unroll
    for (int it = 0; it < 2; ++it) {
        const int p2 = it * 1024 + t;          // 0..2047 local pair
        const int p  = s * 2048 + p2;          // global pair
        const int i  = p >> 6, k = p & (M - 1);
        const float4 bi = box_s[i], bk = box_s[k];
        const float2 ai = af_s[i],  ak = af_s[k];
        const float rel = ai.x * ak.x;
        const float mx = fmaxf(bi.x, bk.x);
        const float my = fmaxf(bi.y, bk.y);
        const float Mx = fminf(bi.z, bk.z);
        const float My = fminf(bi.w, bk.w);
        const float inter = fmaxf(Mx - mx, 0.f) * fmaxf(My - my, 0.f);
        const float iou = inter / (ai.y + ak.y - inter + 1e-12f);
        const float dist = 1.0f - iou;
        ds_s[p2] = plin(3, rel) * plin(4, dist);
        ws_a[n * (M * M) + p] = plin(0, rel) * plin(1, dist);
        dc_local += fabsf(plin(6, dist) - 0.5f);
    }
    {
        float vA = dc_local;
        #pragma unroll
        for (int off = 32; off > 0; off >>= 1) vA += __shfl_down(vA, off, 64);
        if ((t & 63) == 0) ws_dc[n * 32 + s * 16 + (t >> 6)] = vA;
    }
    __syncthreads();

    // triangle product: chunk t (t<544), 32-deep i in local rows [0,32)
    if (t < NCHUNK) {
        int j, k0;
        decode_chunk(t, j, k0);
        float p0 = 1.f, p1 = 1.f, p2 = 1.f, p3 = 1.f;
        #pragma unroll
        for (int ii = 0; ii < 32; ++ii) {
            const float aij = ds_s[ii * M + j];
            const float4 kv = *(const float4*)&ds_s[ii * M + k0];
            p0 *= plin2d(fabsf(aij - kv.x));
            p1 *= plin2d(fabsf(aij - kv.y));
            p2 *= plin2d(fabsf(aij - kv.z));
            p3 *= plin2d(fabsf(aij - kv.w));
        }
        ws4[(n * NS + s) * NCHUNK + t] = make_float4(p0, p1, p2, p3);
    }
}

// ---- Kernel 2: combine partials, row sums, score from precomputed A, epilogue.
// All global reads (ws4, ws_a, ws_dc) hoisted to the top so their L2 latency
// hides under table staging / combine / row-sum phases.
__global__ __launch_bounds__(1024, 4)
void k2_finish(const float* __restrict__ attn,
               const float* __restrict__ fw,
               const float4* __restrict__ ws4,
               const float* __restrict__ ws_a,
               const float* __restrict__ ws_dc,
               float* __restrict__ out)
{
    __shared__ float2 cw_s[8][NSEG + 1];
    __shared__ float att_s[M];
    __shared__ float sim_s[M * SSTRIDE];
    __shared__ float invrs_s[M];
    __shared__ float redB_s[16], redC_s[16];
    __shared__ float redD_s;
    __shared__ float bcast_s[3];

    const int n = blockIdx.x;
    const int t = threadIdx.x;

    // hoisted global loads: independent of all LDS staging
    int j = 0, k0 = 0;
    float4 v0, v1;
    if (t < NCHUNK) {
        decode_chunk(t, j, k0);
        v0 = ws4[(n * NS + 0) * NCHUNK + t];
        v1 = ws4[(n * NS + 1) * NCHUNK + t];
    }
    float av[4];
    #pragma unroll
    for (int it = 0; it < 4; ++it) av[it] = ws_a[n * (M * M) + it * 1024 + t];
    float dcv = (t < 32) ? ws_dc[n * 32 + t] : 0.f;

    STAGE_TABLES();
    if (t < M) att_s[t] = attn[n * M + t];
    __syncthreads();
    DEF_PLINS();

    // att-conf partial + dist-conf combine (wave 0 holds dcv)
    {
        float vB = (t < M) ? fabsf(plin(5, att_s[t]) - 0.5f) : 0.f;
        #pragma unroll
        for (int off = 32; off > 0; off >>= 1) vB += __shfl_down(vB, off, 64);
        if ((t & 63) == 0) redB_s[t >> 6] = vB;
    }
    if (t < 64) {
        float vD = dcv;
        #pragma unroll
        for (int off = 32; off > 0; off >>= 1) vD += __shfl_down(vD, off, 64);
        if (t == 0) redD_s = vD;
    }

    // combine the NS partial products, apply att factor, scatter direct + mirror
    if (t < NCHUNK) {
        const float aj = att_s[j];
        float sv[4];
        sv[0] = v0.x * v1.x * plin2d(fabsf(aj - att_s[k0 + 0]));
        sv[1] = v0.y * v1.y * plin2d(fabsf(aj - att_s[k0 + 1]));
        sv[2] = v0.z * v1.z * plin2d(fabsf(aj - att_s[k0 + 2]));
        sv[3] = v0.w * v1.w * plin2d(fabsf(aj - att_s[k0 + 3]));
        #pragma unroll
        for (int q = 0; q < 4; ++q) {
            const int k = k0 + q;
            sim_s[j * SSTRIDE + k] = sv[q];   // direct
            sim_s[k * SSTRIDE + j] = sv[q];   // mirror (bit-identical by |a-b| symmetry)
        }
    }
    __syncthreads();

    // row sums -> invrs
    {
        const int jr = t >> 4, c = t & 15;
        float psum = sim_s[jr * SSTRIDE + c] + sim_s[jr * SSTRIDE + c + 16] +
                     sim_s[jr * SSTRIDE + c + 32] + sim_s[jr * SSTRIDE + c + 48];
        #pragma unroll
        for (int off = 8; off > 0; off >>= 1) psum += __shfl_down(psum, off, 64);
        if (c == 0) invrs_s[jr] = 1.0f / psum;
    }
    __syncthreads();

    // score pass: A values already in registers
    float sc_local = 0.f;
    #pragma unroll
    for (int it = 0; it < 4; ++it) {
        const int p = it * 1024 + t;
        sc_local += av[it] * (invrs_s[p >> 6] * invrs_s[p & (M - 1)]);
    }
    if (t < M) sc_local += plin(0, att_s[t] * att_s[t]) * invrs_s[t];
    {
        float vC = sc_local;
        #pragma unroll
        for (int off = 32; off > 0; off >>= 1) vC += __shfl_down(vC, off, 64);
        if ((t & 63) == 0) redC_s[t >> 6] = vC;
    }
    __syncthreads();

    if (t == 0) {
        float score_sum = 0.f, acs = 0.f;
        #pragma unroll
        for (int w = 0; w < 16; ++w) { score_sum += redC_s[w]; acs += redB_s[w]; }
        const float dcs = redD_s;
        const float score = sqrtf(score_sum + 1e-20f);
        const float conf = plin(7, acs * (1.0f / M) + dcs * (1.0f / (M * M)));
        const float scc = fminf(fmaxf(score, 0.f), 10.0f);
        const float fl = floorf(scc);
        bcast_s[0] = conf; bcast_s[1] = fl; bcast_s[2] = scc - fl;
    }
    __syncthreads();

    if (t < 11) {
        const float conf = bcast_s[0];
        const int i0 = (int)bcast_s[1];
        const float frac = bcast_s[2];
        const int i1 = i0 > 10 ? 10 : i0;
        const int i2 = (i0 + 1) > 10 ? 10 : (i0 + 1);
        float v = 0.f;
        if (t == i1) v += 1.0f - frac;
        if (t == i2) v += frac;
        out[n * 11 + t] = v * conf;
    }
}

extern "C" void kernel_launch(void* const* d_in, const int* in_sizes, int n_in,
                              void* d_out, int out_size, void* d_ws, size_t ws_size,
                              hipStream_t stream) {
    const float* boxes = (const float*)d_in[0];   // (n,4,64) f32
    const float* attn  = (const float*)d_in[1];   // (n,64)   f32
    const float* fw    = (const float*)d_in[2];   // (16,17)  f32
    float* out = (float*)d_out;                   // (n,11)   f32
    const int n = in_sizes[1] / M;

    float4* ws4  = (float4*)d_ws;                           // n*NS*NCHUNK float4 ~ 2.2 MB
    float* ws_a  = (float*)((char*)d_ws + (4u << 20));      // n*4096 floats = 2 MB at +4 MB
    float* ws_dc = (float*)((char*)d_ws + (8u << 20));      // n*32 floats at +8 MB

    k1_partial<<<dim3(n, NS), dim3(1024), 0, stream>>>(boxes, attn, fw, ws4, ws_a, ws_dc);
    k2_finish<<<dim3(n), dim3(1024), 0, stream>>>(attn, fw, ws4, ws_a, ws_dc, out);
}